// Round 5
// baseline (570.751 us; speedup 1.0000x reference)
//
#include <hip/hip_runtime.h>
#include <hip/hip_bf16.h>

typedef _Float16 half8 __attribute__((ext_vector_type(8)));
typedef _Float16 half4 __attribute__((ext_vector_type(4)));
typedef _Float16 half2v __attribute__((ext_vector_type(2)));
typedef float float4_t __attribute__((ext_vector_type(4)));

// ---------------------------------------------------------------------------
// B=8, P=4096, NC=256, M=32768. Scales: (C,HW) = (128,32768),(256,8192),(512,2048)
// NO transpose pass: the fused kernel gathers its MFMA A-fragments directly
// from raw fp32 feat (8 scalar strided loads per fragment, cvt in-register).
// Pipeline: pack weights (1 small kernel) -> fused gather+MLP+L2norm.
// ---------------------------------------------------------------------------

// Pack (K x 256) fp32 weight into fp16 MFMA B-fragment order:
// step t = k>>5 holds 16KB: idx = ((t*16 + nt)*64 + lane)*8 + j,
// lane = quad(k)*16 + (n&15), j = k&7.  All 6 tensors in ONE launch.
struct PackParams {
    const float* src[6];
    _Float16* dst[6];
};

__global__ void pack_all_kernel(PackParams pp) {
    int bid = blockIdx.x;
    int s, b0;
    if (bid < 128)       { s = 0; b0 = 0;    }   // w1_0: 32768
    else if (bid < 384)  { s = 1; b0 = 128;  }   // w1_1: 65536
    else if (bid < 896)  { s = 2; b0 = 384;  }   // w1_2: 131072
    else if (bid < 1152) { s = 3; b0 = 896;  }   // w2_0: 65536
    else if (bid < 1408) { s = 4; b0 = 1152; }   // w2_1: 65536
    else                 { s = 5; b0 = 1408; }   // w2_2: 65536
    int idx = (bid - b0) * 256 + threadIdx.x;
    const float* w = pp.src[s];
    _Float16* wp = pp.dst[s];
    int k = idx >> 8, n = idx & 255;
    int kt = k >> 5, q = (k >> 3) & 3, j = k & 7;
    int nt = n >> 4, n15 = n & 15;
    int lane = q * 16 + n15;
    wp[(size_t)(((kt * 16 + nt) * 64) + lane) * 8 + j] = (_Float16)w[idx];
}

// ---------------------------------------------------------------------------
// Fused gather + 2-layer MLP + L2 normalize.
// Block = 256 thr = 4 waves; 64 rows x 256 cols. Wave owns 16 rows.
// Layer-1 A-fragments gathered straight from fp32 feat: lane (q,n15) for
// k-step t needs c = t*32 + q*8 .. +8 of column hw(n15) -> 8 loads stride HW.
// ---------------------------------------------------------------------------
struct Params {
    const int* pid[3];
    const float* feat[3];
    const _Float16* w1p[3];
    const float* b1[3];
    const _Float16* w2p;   // 3 scales x 65536 halfs
    const float* b2[3];
    float* out;
};

__device__ __forceinline__ void stage16k(const _Float16* src, _Float16* wbuf, int tid) {
    const float4_t* s4 = (const float4_t*)src;
    float4_t* d4 = (float4_t*)wbuf;
#pragma unroll
    for (int i = 0; i < 4; i++) d4[tid + i * 256] = s4[tid + i * 256];
}

template <int S>
__device__ __forceinline__ void run_scale(const Params& p, int mblk,
                                          _Float16* hbuf, _Float16* wbuf) {
    constexpr int C  = (S == 0) ? 128 : (S == 1) ? 256 : 512;
    constexpr int HW = (S == 0) ? 32768 : (S == 1) ? 8192 : 2048;
    constexpr int NSTEP = C / 32;                 // 4, 8, 16
    constexpr int NHALF = (NSTEP > 8) ? 2 : 1;    // split prefetch for S=2
    constexpr int HSTEP = NSTEP / NHALF;          // <= 8

    int tid  = threadIdx.x;
    int wv   = tid >> 6;
    int lane = tid & 63;
    int q    = (lane >> 4) & 3;
    int n15  = lane & 15;

    int rowA = mblk * 64 + wv * 16 + n15;
    int b  = rowA >> 12;
    int jp = rowA & 4095;
    int hw = p.pid[S][b * 4096 + jp];
    // column base: feat[b, c, hw] = feat[(b*C + c)*HW + hw]
    const float* xcol = p.feat[S] + (size_t)b * C * HW + hw;

    float4_t acc[16];
#pragma unroll
    for (int nt = 0; nt < 16; nt++) acc[nt] = (float4_t){0.f, 0.f, 0.f, 0.f};

    const _Float16* w1p = p.w1p[S];

    // ---------------- Layer 1: K = C ----------------
#pragma unroll
    for (int h = 0; h < NHALF; h++) {
        half8 af[HSTEP];
#pragma unroll
        for (int t = 0; t < HSTEP; t++) {
            int cbase = (h * HSTEP + t) * 32 + q * 8;
            const float* cp = xcol + (size_t)cbase * HW;
            half8 a;
#pragma unroll
            for (int j = 0; j < 8; j++) a[j] = (_Float16)cp[(size_t)j * HW];
            af[t] = a;
        }
#pragma unroll
        for (int t = 0; t < HSTEP; t++) {
            __syncthreads();
            stage16k(w1p + (size_t)(h * HSTEP + t) * 8192, wbuf, tid);
            __syncthreads();
            const half8* wb = (const half8*)wbuf;
#pragma unroll
            for (int nt = 0; nt < 16; nt++)
                acc[nt] = __builtin_amdgcn_mfma_f32_16x16x32_f16(
                    af[t], wb[nt * 64 + lane], acc[nt], 0, 0, 0);
        }
    }

    // ---------------- bias1 + relu -> hbuf fp16 ----------------
    const float* b1 = p.b1[S];
#pragma unroll
    for (int nt = 0; nt < 16; nt++) {
        float bias = b1[nt * 16 + n15];
#pragma unroll
        for (int r = 0; r < 4; r++) {
            float v = fmaxf(acc[nt][r] + bias, 0.f);
            hbuf[(wv * 16 + q * 4 + r) * 260 + nt * 16 + n15] = (_Float16)v;
        }
    }
    // h rows are wave-private: same-wave LDS RAW, no barrier needed.

#pragma unroll
    for (int nt = 0; nt < 16; nt++) acc[nt] = (float4_t){0.f, 0.f, 0.f, 0.f};

    // ---------------- Layer 2: K = 256 ----------------
    const _Float16* w2p = p.w2p + (size_t)S * 65536;
#pragma unroll
    for (int t = 0; t < 8; t++) {
        __syncthreads();
        stage16k(w2p + (size_t)t * 8192, wbuf, tid);
        __syncthreads();
        int kb = t * 32 + q * 8;
        int hoff = (wv * 16 + n15) * 260 + kb;
        half4 lo = *(const half4*)&hbuf[hoff];
        half4 hi = *(const half4*)&hbuf[hoff + 4];
        half8 afr = __builtin_shufflevector(lo, hi, 0, 1, 2, 3, 4, 5, 6, 7);
        const half8* wb = (const half8*)wbuf;
#pragma unroll
        for (int nt = 0; nt < 16; nt++)
            acc[nt] = __builtin_amdgcn_mfma_f32_16x16x32_f16(
                afr, wb[nt * 64 + lane], acc[nt], 0, 0, 0);
    }

    // ---------------- bias2 + L2 norm + store ----------------
    const float* b2 = p.b2[S];
    float ss[4] = {0.f, 0.f, 0.f, 0.f};
#pragma unroll
    for (int nt = 0; nt < 16; nt++) {
        float bias = b2[nt * 16 + n15];
#pragma unroll
        for (int r = 0; r < 4; r++) {
            float v = acc[nt][r] + bias;
            acc[nt][r] = v;
            ss[r] += v * v;
        }
    }
#pragma unroll
    for (int r = 0; r < 4; r++) {
        float t2 = ss[r];
        t2 += __shfl_xor(t2, 1, 64);
        t2 += __shfl_xor(t2, 2, 64);
        t2 += __shfl_xor(t2, 4, 64);
        t2 += __shfl_xor(t2, 8, 64);
        ss[r] = 1.0f / (sqrtf(t2) + 1e-7f);
    }
    float* outp = p.out + (size_t)S * 32768 * 256;
    int rbase = mblk * 64 + wv * 16 + q * 4;
#pragma unroll
    for (int r = 0; r < 4; r++) {
        float inv = ss[r];
        size_t ro = (size_t)(rbase + r) * 256;
#pragma unroll
        for (int nt = 0; nt < 16; nt++)
            outp[ro + nt * 16 + n15] = acc[nt][r] * inv;
    }
}

__launch_bounds__(256, 3)
__global__ void fused_mlp_kernel(Params p) {
    __shared__ __align__(16) _Float16 hbuf[64 * 260];  // 33280 B
    __shared__ __align__(16) _Float16 wbuf[8192];      // 16384 B
    int bid  = blockIdx.x;
    int s    = bid % 3;          // interleave scales across CUs
    int mblk = bid / 3;
    if (s == 0)      run_scale<0>(p, mblk, hbuf, wbuf);
    else if (s == 1) run_scale<1>(p, mblk, hbuf, wbuf);
    else             run_scale<2>(p, mblk, hbuf, wbuf);
}

extern "C" void kernel_launch(void* const* d_in, const int* in_sizes, int n_in,
                              void* d_out, int out_size, void* d_ws, size_t ws_size,
                              hipStream_t stream) {
    const float* feat[3]; const int* pid[3];
    const float* w1[3]; const float* b1[3]; const float* w2[3]; const float* b2[3];
    for (int s = 0; s < 3; s++) {
        feat[s] = (const float*)d_in[6 * s + 0];
        pid[s]  = (const int*)  d_in[6 * s + 1];
        w1[s]   = (const float*)d_in[6 * s + 2];
        b1[s]   = (const float*)d_in[6 * s + 3];
        w2[s]   = (const float*)d_in[6 * s + 4];
        b2[s]   = (const float*)d_in[6 * s + 5];
    }

    // ws layout (halfs): w1p0 | w1p1 | w1p2 | w2p(x3)  — 0.85 MB total
    _Float16* ws = (_Float16*)d_ws;
    _Float16* w1p0   = ws;                    // 32768
    _Float16* w1p1   = ws + 32768;            // 65536
    _Float16* w1p2   = ws + 98304;            // 131072
    _Float16* w2p    = ws + 229376;           // 3*65536 = 196608

    PackParams pp;
    pp.src[0] = w1[0]; pp.dst[0] = w1p0;
    pp.src[1] = w1[1]; pp.dst[1] = w1p1;
    pp.src[2] = w1[2]; pp.dst[2] = w1p2;
    pp.src[3] = w2[0]; pp.dst[3] = w2p;
    pp.src[4] = w2[1]; pp.dst[4] = w2p + 65536;
    pp.src[5] = w2[2]; pp.dst[5] = w2p + 131072;
    pack_all_kernel<<<1664, 256, 0, stream>>>(pp);

    Params p;
    for (int s = 0; s < 3; s++) {
        p.pid[s] = pid[s];
        p.feat[s] = feat[s];
        p.b1[s] = b1[s]; p.b2[s] = b2[s];
    }
    p.w1p[0] = w1p0; p.w1p[1] = w1p1; p.w1p[2] = w1p2;
    p.w2p = w2p;
    p.out = (float*)d_out;

    fused_mlp_kernel<<<1536, 256, 0, stream>>>(p);
}

// Round 6
// 386.576 us; speedup vs baseline: 1.4764x; 1.4764x over previous
//
#include <hip/hip_runtime.h>
#include <hip/hip_bf16.h>

typedef _Float16 half8 __attribute__((ext_vector_type(8)));
typedef _Float16 half4 __attribute__((ext_vector_type(4)));
typedef _Float16 half2v __attribute__((ext_vector_type(2)));
typedef float float4_t __attribute__((ext_vector_type(4)));

// ---------------------------------------------------------------------------
// B=8, P=4096, NC=256, M=32768. Scales: (C,HW) = (128,32768),(256,8192),(512,2048)
// D1: transpose-GATHER: coalesced feat tile -> LDS -> write ONLY gathered
//     patch rows into gx[s] (M x C fp16, patch-order).  + weight pack.
// D2: fused MLP+L2norm reading gx sequentially (no indirection).
// ---------------------------------------------------------------------------

struct TGParams {
    const float* feat[3];
    const int* pid[3];
    _Float16* gx[3];
    const float* wsrc[6];
    _Float16* wdst[6];
};

__launch_bounds__(256, 4)
__global__ void transpose_gather_pack_kernel(TGParams tp) {
    __shared__ __align__(16) _Float16 lds[64 * 266];   // 34048 B
    int bid = blockIdx.x;
    if (bid < 3584) {
        // ---- transpose-gather path ----
        int s, rem, C, HW;
        if (bid < 2048)      { s = 0; rem = bid;        C = 128; HW = 32768; }
        else if (bid < 3072) { s = 1; rem = bid - 2048; C = 256; HW = 8192;  }
        else                 { s = 2; rem = bid - 3072; C = 512; HW = 2048;  }
        int hwTiles = HW >> 8;                 // 256-wide hw tiles
        int tilesPerB = hwTiles * (C >> 6);
        int b  = rem / tilesPerB;
        int r2 = rem - b * tilesPerB;
        int ct  = r2 / hwTiles;
        int hwt = r2 - ct * hwTiles;
        int c0 = ct << 6, hw0 = hwt << 8;

        int t = threadIdx.x;
        int wv = t >> 6, col4 = t & 63;        // wave reads one full row segment
        const float* src = tp.feat[s] + ((size_t)b * C + c0) * HW + hw0 + col4 * 4;

        // phase 1: 64 c-rows x 256 hw floats -> LDS fp16 (round-1 proven body)
#pragma unroll
        for (int batch = 0; batch < 2; batch++) {
            float4_t v[8];
#pragma unroll
            for (int u = 0; u < 8; u++) {
                int r = (batch * 8 + u) * 4 + wv;          // c-row within tile
                v[u] = *(const float4_t*)(src + (size_t)r * HW);
            }
#pragma unroll
            for (int u = 0; u < 8; u++) {
                int r = (batch * 8 + u) * 4 + wv;
                int lo = r * 266 + col4 * 4;
                half2v a, b2;
                a[0]  = (_Float16)v[u][0]; a[1]  = (_Float16)v[u][1];
                b2[0] = (_Float16)v[u][2]; b2[1] = (_Float16)v[u][3];
                *(half2v*)&lds[lo]     = a;
                *(half2v*)&lds[lo + 2] = b2;
            }
        }
        __syncthreads();
        // phase 2: scan pid of this batch; for each patch whose hw is in this
        // tile, write its 64-c segment (128 B) into gx[patch row].
        const int* pidb = tp.pid[s] + b * 4096;
        _Float16* gx = tp.gx[s];
#pragma unroll 1
        for (int j = t; j < 4096; j += 256) {
            int off = pidb[j] - hw0;
            if ((unsigned)off < 256u) {
                _Float16* dst = gx + (size_t)(b * 4096 + j) * C + c0;
#pragma unroll
                for (int k8 = 0; k8 < 8; k8++) {
                    half8 h;
#pragma unroll
                    for (int k = 0; k < 8; k++)
                        h[k] = lds[(k8 * 8 + k) * 266 + off];
                    *(half8*)&dst[k8 * 8] = h;
                }
            }
        }
        return;
    }
    // ---- weight pack path (proven body, no barriers) ----
    int pbid = bid - 3584;
    int s, b0;
    if (pbid < 128)       { s = 0; b0 = 0;    }   // w1_0: 32768
    else if (pbid < 384)  { s = 1; b0 = 128;  }   // w1_1: 65536
    else if (pbid < 896)  { s = 2; b0 = 384;  }   // w1_2: 131072
    else if (pbid < 1152) { s = 3; b0 = 896;  }   // w2_0: 65536
    else if (pbid < 1408) { s = 4; b0 = 1152; }   // w2_1: 65536
    else                  { s = 5; b0 = 1408; }   // w2_2: 65536
    int idx = (pbid - b0) * 256 + threadIdx.x;
    const float* w = tp.wsrc[s];
    _Float16* wp = tp.wdst[s];
    int k = idx >> 8, n = idx & 255;
    int kt = k >> 5, q = (k >> 3) & 3, j = k & 7;
    int nt = n >> 4, n15 = n & 15;
    int lane = q * 16 + n15;
    wp[(size_t)(((kt * 16 + nt) * 64) + lane) * 8 + j] = (_Float16)w[idx];
}

// ---------------------------------------------------------------------------
// Fused MLP + L2 normalize, reading pre-gathered gx rows SEQUENTIALLY.
// Block = 256 thr = 4 waves; 64 rows x 256 cols. Wave owns 16 rows.
// ---------------------------------------------------------------------------
struct Params {
    const _Float16* gx[3];
    const _Float16* w1p[3];
    const float* b1[3];
    const _Float16* w2p;   // 3 scales x 65536 halfs
    const float* b2[3];
    float* out;
};

__device__ __forceinline__ void stage16k(const _Float16* src, _Float16* wbuf, int tid) {
    const float4_t* s4 = (const float4_t*)src;
    float4_t* d4 = (float4_t*)wbuf;
#pragma unroll
    for (int i = 0; i < 4; i++) d4[tid + i * 256] = s4[tid + i * 256];
}

template <int S>
__device__ __forceinline__ void run_scale(const Params& p, int mblk,
                                          _Float16* hbuf, _Float16* wbuf) {
    constexpr int C  = (S == 0) ? 128 : (S == 1) ? 256 : 512;
    constexpr int NSTEP = C / 32;                 // 4, 8, 16
    constexpr int NHALF = (NSTEP > 8) ? 2 : 1;    // split prefetch for S=2
    constexpr int HSTEP = NSTEP / NHALF;          // <= 8

    int tid  = threadIdx.x;
    int wv   = tid >> 6;
    int lane = tid & 63;
    int q    = (lane >> 4) & 3;
    int n15  = lane & 15;

    int rowA = mblk * 64 + wv * 16 + n15;
    const _Float16* xrow = p.gx[S] + (size_t)rowA * C;

    float4_t acc[16];
#pragma unroll
    for (int nt = 0; nt < 16; nt++) acc[nt] = (float4_t){0.f, 0.f, 0.f, 0.f};

    const _Float16* w1p = p.w1p[S];

    // ---------------- Layer 1: K = C ----------------
#pragma unroll
    for (int h = 0; h < NHALF; h++) {
        half8 af[HSTEP];
#pragma unroll
        for (int t = 0; t < HSTEP; t++)
            af[t] = *(const half8*)(xrow + (h * HSTEP + t) * 32 + q * 8);
#pragma unroll
        for (int t = 0; t < HSTEP; t++) {
            __syncthreads();
            stage16k(w1p + (size_t)(h * HSTEP + t) * 8192, wbuf, tid);
            __syncthreads();
            const half8* wb = (const half8*)wbuf;
#pragma unroll
            for (int nt = 0; nt < 16; nt++)
                acc[nt] = __builtin_amdgcn_mfma_f32_16x16x32_f16(
                    af[t], wb[nt * 64 + lane], acc[nt], 0, 0, 0);
        }
    }

    // ---------------- bias1 + relu -> hbuf fp16 ----------------
    const float* b1 = p.b1[S];
#pragma unroll
    for (int nt = 0; nt < 16; nt++) {
        float bias = b1[nt * 16 + n15];
#pragma unroll
        for (int r = 0; r < 4; r++) {
            float v = fmaxf(acc[nt][r] + bias, 0.f);
            hbuf[(wv * 16 + q * 4 + r) * 260 + nt * 16 + n15] = (_Float16)v;
        }
    }
    // h rows are wave-private: same-wave LDS RAW, no barrier needed.

#pragma unroll
    for (int nt = 0; nt < 16; nt++) acc[nt] = (float4_t){0.f, 0.f, 0.f, 0.f};

    // ---------------- Layer 2: K = 256 ----------------
    const _Float16* w2p = p.w2p + (size_t)S * 65536;
#pragma unroll
    for (int t = 0; t < 8; t++) {
        __syncthreads();
        stage16k(w2p + (size_t)t * 8192, wbuf, tid);
        __syncthreads();
        int kb = t * 32 + q * 8;
        int hoff = (wv * 16 + n15) * 260 + kb;
        half4 lo = *(const half4*)&hbuf[hoff];
        half4 hi = *(const half4*)&hbuf[hoff + 4];
        half8 afr = __builtin_shufflevector(lo, hi, 0, 1, 2, 3, 4, 5, 6, 7);
        const half8* wb = (const half8*)wbuf;
#pragma unroll
        for (int nt = 0; nt < 16; nt++)
            acc[nt] = __builtin_amdgcn_mfma_f32_16x16x32_f16(
                afr, wb[nt * 64 + lane], acc[nt], 0, 0, 0);
    }

    // ---------------- bias2 + L2 norm + store ----------------
    const float* b2 = p.b2[S];
    float ss[4] = {0.f, 0.f, 0.f, 0.f};
#pragma unroll
    for (int nt = 0; nt < 16; nt++) {
        float bias = b2[nt * 16 + n15];
#pragma unroll
        for (int r = 0; r < 4; r++) {
            float v = acc[nt][r] + bias;
            acc[nt][r] = v;
            ss[r] += v * v;
        }
    }
#pragma unroll
    for (int r = 0; r < 4; r++) {
        float t2 = ss[r];
        t2 += __shfl_xor(t2, 1, 64);
        t2 += __shfl_xor(t2, 2, 64);
        t2 += __shfl_xor(t2, 4, 64);
        t2 += __shfl_xor(t2, 8, 64);
        ss[r] = 1.0f / (sqrtf(t2) + 1e-7f);
    }
    float* outp = p.out + (size_t)S * 32768 * 256;
    int rbase = mblk * 64 + wv * 16 + q * 4;
#pragma unroll
    for (int r = 0; r < 4; r++) {
        float inv = ss[r];
        size_t ro = (size_t)(rbase + r) * 256;
#pragma unroll
        for (int nt = 0; nt < 16; nt++)
            outp[ro + nt * 16 + n15] = acc[nt][r] * inv;
    }
}

__launch_bounds__(256, 3)
__global__ void fused_mlp_kernel(Params p) {
    __shared__ __align__(16) _Float16 hbuf[64 * 260];  // 33280 B
    __shared__ __align__(16) _Float16 wbuf[8192];      // 16384 B
    int bid  = blockIdx.x;
    int s    = bid % 3;          // interleave scales across CUs
    int mblk = bid / 3;
    if (s == 0)      run_scale<0>(p, mblk, hbuf, wbuf);
    else if (s == 1) run_scale<1>(p, mblk, hbuf, wbuf);
    else             run_scale<2>(p, mblk, hbuf, wbuf);
}

extern "C" void kernel_launch(void* const* d_in, const int* in_sizes, int n_in,
                              void* d_out, int out_size, void* d_ws, size_t ws_size,
                              hipStream_t stream) {
    const float* feat[3]; const int* pid[3];
    const float* w1[3]; const float* b1[3]; const float* w2[3]; const float* b2[3];
    for (int s = 0; s < 3; s++) {
        feat[s] = (const float*)d_in[6 * s + 0];
        pid[s]  = (const int*)  d_in[6 * s + 1];
        w1[s]   = (const float*)d_in[6 * s + 2];
        b1[s]   = (const float*)d_in[6 * s + 3];
        w2[s]   = (const float*)d_in[6 * s + 4];
        b2[s]   = (const float*)d_in[6 * s + 5];
    }

    // ws layout (halfs): w1p0 | w1p1 | w1p2 | w2p(x3) | gx0 | gx1 | gx2
    _Float16* ws = (_Float16*)d_ws;
    _Float16* w1p0 = ws;                      // 32768
    _Float16* w1p1 = ws + 32768;              // 65536
    _Float16* w1p2 = ws + 98304;              // 131072
    _Float16* w2p  = ws + 229376;             // 3*65536 = 196608
    _Float16* gx0  = ws + 425984;             // 32768*128 = 4194304
    _Float16* gx1  = ws + 4620288;            // 32768*256 = 8388608
    _Float16* gx2  = ws + 13008896;           // 32768*512 = 16777216
    // total: 29786112 halfs = 59.6 MB

    TGParams tg;
    for (int s = 0; s < 3; s++) { tg.feat[s] = feat[s]; tg.pid[s] = pid[s]; }
    tg.gx[0] = gx0; tg.gx[1] = gx1; tg.gx[2] = gx2;
    tg.wsrc[0] = w1[0]; tg.wdst[0] = w1p0;
    tg.wsrc[1] = w1[1]; tg.wdst[1] = w1p1;
    tg.wsrc[2] = w1[2]; tg.wdst[2] = w1p2;
    tg.wsrc[3] = w2[0]; tg.wdst[3] = w2p;
    tg.wsrc[4] = w2[1]; tg.wdst[4] = w2p + 65536;
    tg.wsrc[5] = w2[2]; tg.wdst[5] = w2p + 131072;
    // 3584 transpose-gather blocks + 1664 pack blocks
    transpose_gather_pack_kernel<<<5248, 256, 0, stream>>>(tg);

    Params p;
    for (int s = 0; s < 3; s++) { p.b1[s] = b1[s]; p.b2[s] = b2[s]; }
    p.gx[0] = gx0; p.gx[1] = gx1; p.gx[2] = gx2;
    p.w1p[0] = w1p0; p.w1p[1] = w1p1; p.w1p[2] = w1p2;
    p.w2p = w2p;
    p.out = (float*)d_out;

    fused_mlp_kernel<<<1536, 256, 0, stream>>>(p);
}

// Round 7
// 382.023 us; speedup vs baseline: 1.4940x; 1.0119x over previous
//
#include <hip/hip_runtime.h>
#include <hip/hip_bf16.h>

typedef _Float16 half8 __attribute__((ext_vector_type(8)));
typedef _Float16 half4 __attribute__((ext_vector_type(4)));
typedef _Float16 half2v __attribute__((ext_vector_type(2)));
typedef float float4_t __attribute__((ext_vector_type(4)));

// ---------------------------------------------------------------------------
// B=8, P=4096, NC=256, M=32768. Scales: (C,HW) = (128,32768),(256,8192),(512,2048)
// D1: transpose-GATHER: coalesced feat tile -> LDS -> compact hit list ->
//     dense cooperative write of gathered patch rows into gx[s].  + pack.
// D2: fused MLP+L2norm reading gx sequentially (no indirection).
// ---------------------------------------------------------------------------

struct TGParams {
    const float* feat[3];
    const int* pid[3];
    _Float16* gx[3];
    const float* wsrc[6];
    _Float16* wdst[6];
};

__launch_bounds__(256, 4)
__global__ void transpose_gather_pack_kernel(TGParams tp) {
    __shared__ __align__(16) _Float16 lds[64 * 266];   // 34048 B
    __shared__ int hlist[1280];                        // 5120 B
    __shared__ int nhit;
    int bid = blockIdx.x;
    if (bid < 3584) {
        // ---- transpose-gather path ----
        int s, rem, C, HW;
        if (bid < 2048)      { s = 0; rem = bid;        C = 128; HW = 32768; }
        else if (bid < 3072) { s = 1; rem = bid - 2048; C = 256; HW = 8192;  }
        else                 { s = 2; rem = bid - 3072; C = 512; HW = 2048;  }
        int hwTiles = HW >> 8;                 // 256-wide hw tiles
        int tilesPerB = hwTiles * (C >> 6);
        int b  = rem / tilesPerB;
        int r2 = rem - b * tilesPerB;
        int ct  = r2 / hwTiles;
        int hwt = r2 - ct * hwTiles;
        int c0 = ct << 6, hw0 = hwt << 8;

        int t = threadIdx.x;
        if (t == 0) nhit = 0;
        int wv = t >> 6, col4 = t & 63;        // wave reads one full row segment
        const float* src = tp.feat[s] + ((size_t)b * C + c0) * HW + hw0 + col4 * 4;

        // phase 1: 64 c-rows x 256 hw floats -> LDS fp16 (proven body)
#pragma unroll
        for (int batch = 0; batch < 2; batch++) {
            float4_t v[8];
#pragma unroll
            for (int u = 0; u < 8; u++) {
                int r = (batch * 8 + u) * 4 + wv;          // c-row within tile
                v[u] = *(const float4_t*)(src + (size_t)r * HW);
            }
#pragma unroll
            for (int u = 0; u < 8; u++) {
                int r = (batch * 8 + u) * 4 + wv;
                int lo = r * 266 + col4 * 4;
                half2v a, b2;
                a[0]  = (_Float16)v[u][0]; a[1]  = (_Float16)v[u][1];
                b2[0] = (_Float16)v[u][2]; b2[1] = (_Float16)v[u][3];
                *(half2v*)&lds[lo]     = a;
                *(half2v*)&lds[lo + 2] = b2;
            }
        }
        __syncthreads();   // LDS tile ready + nhit reset visible

        // phase 2a: scan pid, compact hits (j, off) into LDS list
        const int* pidb = tp.pid[s] + b * 4096;
#pragma unroll 1
        for (int j = t; j < 4096; j += 256) {
            int off = pidb[j] - hw0;
            if ((unsigned)off < 256u) {
                int idx = atomicAdd(&nhit, 1);
                if (idx < 1280) hlist[idx] = (j << 8) | off;
            }
        }
        __syncthreads();

        // phase 2b: dense cooperative gather: nhit*8 chunk items, all lanes busy
        _Float16* gx = tp.gx[s];
        int nh = nhit;
        if (nh > 1280) nh = 1280;
        int total = nh * 8;
#pragma unroll 1
        for (int m = t; m < total; m += 256) {
            int e   = hlist[m >> 3];
            int k8  = m & 7;
            int j   = e >> 8;
            int off = e & 255;
            half8 h;
#pragma unroll
            for (int k = 0; k < 8; k++)
                h[k] = lds[(k8 * 8 + k) * 266 + off];
            *(half8*)(gx + (size_t)(b * 4096 + j) * C + c0 + k8 * 8) = h;
        }
        return;
    }
    // ---- weight pack path (proven body, no barriers) ----
    int pbid = bid - 3584;
    int s, b0;
    if (pbid < 128)       { s = 0; b0 = 0;    }   // w1_0: 32768
    else if (pbid < 384)  { s = 1; b0 = 128;  }   // w1_1: 65536
    else if (pbid < 896)  { s = 2; b0 = 384;  }   // w1_2: 131072
    else if (pbid < 1152) { s = 3; b0 = 896;  }   // w2_0: 65536
    else if (pbid < 1408) { s = 4; b0 = 1152; }   // w2_1: 65536
    else                  { s = 5; b0 = 1408; }   // w2_2: 65536
    int idx = (pbid - b0) * 256 + threadIdx.x;
    const float* w = tp.wsrc[s];
    _Float16* wp = tp.wdst[s];
    int k = idx >> 8, n = idx & 255;
    int kt = k >> 5, q = (k >> 3) & 3, j = k & 7;
    int nt = n >> 4, n15 = n & 15;
    int lane = q * 16 + n15;
    wp[(size_t)(((kt * 16 + nt) * 64) + lane) * 8 + j] = (_Float16)w[idx];
}

// ---------------------------------------------------------------------------
// Fused MLP + L2 normalize, reading pre-gathered gx rows SEQUENTIALLY.
// Block = 256 thr = 4 waves; 64 rows x 256 cols. Wave owns 16 rows.
// ---------------------------------------------------------------------------
struct Params {
    const _Float16* gx[3];
    const _Float16* w1p[3];
    const float* b1[3];
    const _Float16* w2p;   // 3 scales x 65536 halfs
    const float* b2[3];
    float* out;
};

__device__ __forceinline__ void stage16k(const _Float16* src, _Float16* wbuf, int tid) {
    const float4_t* s4 = (const float4_t*)src;
    float4_t* d4 = (float4_t*)wbuf;
#pragma unroll
    for (int i = 0; i < 4; i++) d4[tid + i * 256] = s4[tid + i * 256];
}

template <int S>
__device__ __forceinline__ void run_scale(const Params& p, int mblk,
                                          _Float16* hbuf, _Float16* wbuf) {
    constexpr int C  = (S == 0) ? 128 : (S == 1) ? 256 : 512;
    constexpr int NSTEP = C / 32;                 // 4, 8, 16
    constexpr int NHALF = (NSTEP > 8) ? 2 : 1;    // split prefetch for S=2
    constexpr int HSTEP = NSTEP / NHALF;          // <= 8

    int tid  = threadIdx.x;
    int wv   = tid >> 6;
    int lane = tid & 63;
    int q    = (lane >> 4) & 3;
    int n15  = lane & 15;

    int rowA = mblk * 64 + wv * 16 + n15;
    const _Float16* xrow = p.gx[S] + (size_t)rowA * C;

    float4_t acc[16];
#pragma unroll
    for (int nt = 0; nt < 16; nt++) acc[nt] = (float4_t){0.f, 0.f, 0.f, 0.f};

    const _Float16* w1p = p.w1p[S];

    // ---------------- Layer 1: K = C ----------------
#pragma unroll
    for (int h = 0; h < NHALF; h++) {
        half8 af[HSTEP];
#pragma unroll
        for (int t = 0; t < HSTEP; t++)
            af[t] = *(const half8*)(xrow + (h * HSTEP + t) * 32 + q * 8);
#pragma unroll
        for (int t = 0; t < HSTEP; t++) {
            __syncthreads();
            stage16k(w1p + (size_t)(h * HSTEP + t) * 8192, wbuf, tid);
            __syncthreads();
            const half8* wb = (const half8*)wbuf;
#pragma unroll
            for (int nt = 0; nt < 16; nt++)
                acc[nt] = __builtin_amdgcn_mfma_f32_16x16x32_f16(
                    af[t], wb[nt * 64 + lane], acc[nt], 0, 0, 0);
        }
    }

    // ---------------- bias1 + relu -> hbuf fp16 ----------------
    const float* b1 = p.b1[S];
#pragma unroll
    for (int nt = 0; nt < 16; nt++) {
        float bias = b1[nt * 16 + n15];
#pragma unroll
        for (int r = 0; r < 4; r++) {
            float v = fmaxf(acc[nt][r] + bias, 0.f);
            hbuf[(wv * 16 + q * 4 + r) * 260 + nt * 16 + n15] = (_Float16)v;
        }
    }
    // h rows are wave-private: same-wave LDS RAW, no barrier needed.

#pragma unroll
    for (int nt = 0; nt < 16; nt++) acc[nt] = (float4_t){0.f, 0.f, 0.f, 0.f};

    // ---------------- Layer 2: K = 256 ----------------
    const _Float16* w2p = p.w2p + (size_t)S * 65536;
#pragma unroll
    for (int t = 0; t < 8; t++) {
        __syncthreads();
        stage16k(w2p + (size_t)t * 8192, wbuf, tid);
        __syncthreads();
        int kb = t * 32 + q * 8;
        int hoff = (wv * 16 + n15) * 260 + kb;
        half4 lo = *(const half4*)&hbuf[hoff];
        half4 hi = *(const half4*)&hbuf[hoff + 4];
        half8 afr = __builtin_shufflevector(lo, hi, 0, 1, 2, 3, 4, 5, 6, 7);
        const half8* wb = (const half8*)wbuf;
#pragma unroll
        for (int nt = 0; nt < 16; nt++)
            acc[nt] = __builtin_amdgcn_mfma_f32_16x16x32_f16(
                afr, wb[nt * 64 + lane], acc[nt], 0, 0, 0);
    }

    // ---------------- bias2 + L2 norm + store ----------------
    const float* b2 = p.b2[S];
    float ss[4] = {0.f, 0.f, 0.f, 0.f};
#pragma unroll
    for (int nt = 0; nt < 16; nt++) {
        float bias = b2[nt * 16 + n15];
#pragma unroll
        for (int r = 0; r < 4; r++) {
            float v = acc[nt][r] + bias;
            acc[nt][r] = v;
            ss[r] += v * v;
        }
    }
#pragma unroll
    for (int r = 0; r < 4; r++) {
        float t2 = ss[r];
        t2 += __shfl_xor(t2, 1, 64);
        t2 += __shfl_xor(t2, 2, 64);
        t2 += __shfl_xor(t2, 4, 64);
        t2 += __shfl_xor(t2, 8, 64);
        ss[r] = 1.0f / (sqrtf(t2) + 1e-7f);
    }
    float* outp = p.out + (size_t)S * 32768 * 256;
    int rbase = mblk * 64 + wv * 16 + q * 4;
#pragma unroll
    for (int r = 0; r < 4; r++) {
        float inv = ss[r];
        size_t ro = (size_t)(rbase + r) * 256;
#pragma unroll
        for (int nt = 0; nt < 16; nt++)
            outp[ro + nt * 16 + n15] = acc[nt][r] * inv;
    }
}

__launch_bounds__(256, 3)
__global__ void fused_mlp_kernel(Params p) {
    __shared__ __align__(16) _Float16 hbuf[64 * 260];  // 33280 B
    __shared__ __align__(16) _Float16 wbuf[8192];      // 16384 B
    int bid  = blockIdx.x;
    int s    = bid % 3;          // interleave scales across CUs
    int mblk = bid / 3;
    if (s == 0)      run_scale<0>(p, mblk, hbuf, wbuf);
    else if (s == 1) run_scale<1>(p, mblk, hbuf, wbuf);
    else             run_scale<2>(p, mblk, hbuf, wbuf);
}

extern "C" void kernel_launch(void* const* d_in, const int* in_sizes, int n_in,
                              void* d_out, int out_size, void* d_ws, size_t ws_size,
                              hipStream_t stream) {
    const float* feat[3]; const int* pid[3];
    const float* w1[3]; const float* b1[3]; const float* w2[3]; const float* b2[3];
    for (int s = 0; s < 3; s++) {
        feat[s] = (const float*)d_in[6 * s + 0];
        pid[s]  = (const int*)  d_in[6 * s + 1];
        w1[s]   = (const float*)d_in[6 * s + 2];
        b1[s]   = (const float*)d_in[6 * s + 3];
        w2[s]   = (const float*)d_in[6 * s + 4];
        b2[s]   = (const float*)d_in[6 * s + 5];
    }

    // ws layout (halfs): w1p0 | w1p1 | w1p2 | w2p(x3) | gx0 | gx1 | gx2
    _Float16* ws = (_Float16*)d_ws;
    _Float16* w1p0 = ws;                      // 32768
    _Float16* w1p1 = ws + 32768;              // 65536
    _Float16* w1p2 = ws + 98304;              // 131072
    _Float16* w2p  = ws + 229376;             // 3*65536 = 196608
    _Float16* gx0  = ws + 425984;             // 32768*128 = 4194304
    _Float16* gx1  = ws + 4620288;            // 32768*256 = 8388608
    _Float16* gx2  = ws + 13008896;           // 32768*512 = 16777216
    // total: 29786112 halfs = 59.6 MB

    TGParams tg;
    for (int s = 0; s < 3; s++) { tg.feat[s] = feat[s]; tg.pid[s] = pid[s]; }
    tg.gx[0] = gx0; tg.gx[1] = gx1; tg.gx[2] = gx2;
    tg.wsrc[0] = w1[0]; tg.wdst[0] = w1p0;
    tg.wsrc[1] = w1[1]; tg.wdst[1] = w1p1;
    tg.wsrc[2] = w1[2]; tg.wdst[2] = w1p2;
    tg.wsrc[3] = w2[0]; tg.wdst[3] = w2p;
    tg.wsrc[4] = w2[1]; tg.wdst[4] = w2p + 65536;
    tg.wsrc[5] = w2[2]; tg.wdst[5] = w2p + 131072;
    // 3584 transpose-gather blocks + 1664 pack blocks
    transpose_gather_pack_kernel<<<5248, 256, 0, stream>>>(tg);

    Params p;
    for (int s = 0; s < 3; s++) { p.b1[s] = b1[s]; p.b2[s] = b2[s]; }
    p.gx[0] = gx0; p.gx[1] = gx1; p.gx[2] = gx2;
    p.w1p[0] = w1p0; p.w1p[1] = w1p1; p.w1p[2] = w1p2;
    p.w2p = w2p;
    p.out = (float*)d_out;

    fused_mlp_kernel<<<1536, 256, 0, stream>>>(p);
}